// Round 2
// baseline (1197.110 us; speedup 1.0000x reference)
//
#include <hip/hip_runtime.h>

#define BB 16
#define HH 256
#define LL 4096
#define NN2 32

static constexpr float BN_EPS = 1e-5f;

__device__ __forceinline__ float gelu_exact(float v) {
    return 0.5f * v * (1.0f + erff(v * 0.70710678118654752f));
}
__device__ __forceinline__ float sigmoidf_(float v) {
    return 1.0f / (1.0f + expf(-v));
}

// ---------------------------------------------------------------------------
// K0: per-(h,n) SSM constants.
// cst layout (each 8192 floats): [0]=w_re [1]=w_im [2]=c0_re [3]=c0_im [4]=c1_re [5]=c1_im
// Ceff = 2 * (C_re + i C_im) * (exp(dtA) - 1) / A   (factor 2 from 2*Re(...))
// ---------------------------------------------------------------------------
__global__ void k_consts(const float* __restrict__ log_dt,
                         const float* __restrict__ logA_re,
                         const float* __restrict__ A_im,
                         const float* __restrict__ C_re,
                         const float* __restrict__ C_im,
                         float* __restrict__ cst) {
    int idx = blockIdx.x * blockDim.x + threadIdx.x;
    if (idx >= HH * NN2) return;
    int h = idx / NN2;
    float dt = expf(log_dt[h]);
    float Ar = -expf(logA_re[idx]);
    float Ai = A_im[idx];
    float er = expf(dt * Ar);
    float wr = er * cosf(dt * Ai);
    float wi = er * sinf(dt * Ai);
    float Er = wr - 1.0f, Ei = wi;
    float inv = 1.0f / (Ar * Ar + Ai * Ai);
    float Fr = (Er * Ar + Ei * Ai) * inv;
    float Fi = (Ei * Ar - Er * Ai) * inv;
    cst[idx] = wr;
    cst[8192 + idx] = wi;
    #pragma unroll
    for (int c = 0; c < 2; ++c) {
        float Cr = C_re[c * HH * NN2 + idx], Ci = C_im[c * HH * NN2 + idx];
        cst[8192 * (2 + 2 * c) + idx] = 2.0f * (Cr * Fr - Ci * Fi);
        cst[8192 * (3 + 2 * c) + idx] = 2.0f * (Cr * Fi + Ci * Fr);
    }
}

// ---------------------------------------------------------------------------
// K2: bidirectional diagonal-SSM scan. One wave per (b,h) row.
// lanes 0..31: forward recurrence  s[l]   = w*s[l-1] + xbn[l],  out[l]   += 2Re(C0 s)
// lanes 32..63: backward recurrence t'[l] = w*t'[l+1] + xbn[l], out[l-1] += 2Re(C1 t')
// Contributions buffered in LDS [2][32][33] for 32 steps, then column-summed
// and atomically added into ycomb (zeroed; exactly 2 commutative adds/loc).
// ---------------------------------------------------------------------------
__global__ __launch_bounds__(64) void k_scan(const float* __restrict__ x,
                                             const float* __restrict__ g1,
                                             const float* __restrict__ b1,
                                             const float* __restrict__ m1,
                                             const float* __restrict__ v1,
                                             const float* __restrict__ cst,
                                             float* __restrict__ ycomb) {
    __shared__ float cbuf[2 * 32 * 33];
    int bh = blockIdx.x;
    int h = bh % HH;
    int lane = threadIdx.x;
    int half = lane >> 5;
    int n = lane & 31;
    int hn = h * NN2 + n;

    float wr = cst[hn];
    float wi = cst[8192 + hn];
    float Cr = cst[8192 * (2 + 2 * half) + hn];
    float Ci = cst[8192 * (3 + 2 * half) + hn];

    float sc = g1[h] * rsqrtf(v1[h] + BN_EPS);
    float sh = fmaf(-m1[h], sc, b1[h]);

    const float* q = x + (size_t)bh * LL + (half ? (LL - 1) : 0);
    int stepdir = half ? -1 : 1;
    float* rowout = ycomb + (size_t)bh * LL;

    float sr = 0.0f, si = 0.0f;
    int lbase = half * 1056 + n * 33;

    for (int c = 0; c < LL / 32; ++c) {
        #pragma unroll
        for (int j = 0; j < 32; ++j) {
            float xv = fmaf(q[0], sc, sh);
            q += stepdir;
            float t0 = fmaf(wr, sr, xv);
            float nsi = fmaf(wi, sr, wr * si);
            sr = fmaf(-wi, si, t0);
            si = nsi;
            cbuf[lbase + j] = fmaf(Cr, sr, -(Ci * si));
        }
        __syncthreads();
        float sum = 0.0f;
        #pragma unroll
        for (int m = 0; m < 32; ++m) sum += cbuf[half * 1056 + m * 33 + n];
        int gl = c * 32 + n;
        int oidx = half ? (LL - 2 - gl) : gl;
        if (oidx >= 0) atomicAdd(rowout + oidx, sum);
        __syncthreads();
    }
}

// ---------------------------------------------------------------------------
// K2b: in-place  y <- gelu(y + D[h] * bn1(x))
// ---------------------------------------------------------------------------
__global__ void k_combine(const float* __restrict__ x,
                          const float* __restrict__ g1,
                          const float* __restrict__ b1,
                          const float* __restrict__ m1,
                          const float* __restrict__ v1,
                          const float* __restrict__ D,
                          float* __restrict__ y) {
    int i4 = blockIdx.x * blockDim.x + threadIdx.x;
    if (i4 >= BB * HH * LL / 4) return;
    int row = i4 >> 10;          // L/4 = 1024 float4 per row
    int h = row & (HH - 1);
    float sc = g1[h] * rsqrtf(v1[h] + BN_EPS);
    float sh = fmaf(-m1[h], sc, b1[h]);
    float d = D[h];
    float4 xv = ((const float4*)x)[i4];
    float4 yv = ((float4*)y)[i4];
    yv.x = gelu_exact(fmaf(d, fmaf(xv.x, sc, sh), yv.x));
    yv.y = gelu_exact(fmaf(d, fmaf(xv.y, sc, sh), yv.y));
    yv.z = gelu_exact(fmaf(d, fmaf(xv.z, sc, sh), yv.z));
    yv.w = gelu_exact(fmaf(d, fmaf(xv.w, sc, sh), yv.w));
    ((float4*)y)[i4] = yv;
}

// ---------------------------------------------------------------------------
// Tiled f32 GEMM, 128 rows x 64 cols per block, K_TILE=32, 256 threads,
// 2x4x4 accs/thread. Rows split so each thread owns rows r and r+64 of the
// tile (MODE 0 uses that to keep GLU pairs o / o+256 in one thread).
// MODE 0: Out = X + glu(Wo @ Bm + bias)            (Out=d_out, X=x)
// MODE 1: Out = gelu(W2 @ bn2(Bm) + bias)          (Out=h2, Bm=x1)
// MODE 2: Out = X + (W3 @ Bm) + bias               (Out=X=d_out in-place)
// ---------------------------------------------------------------------------
template <int MODE>
__global__ __launch_bounds__(256) void k_gemm(const float* __restrict__ A,
                                              const float* __restrict__ Bm,
                                              const float* __restrict__ bias,
                                              const float* __restrict__ X,
                                              const float* __restrict__ bng,
                                              const float* __restrict__ bnb,
                                              const float* __restrict__ bnm,
                                              const float* __restrict__ bnv,
                                              float* __restrict__ Out) {
    constexpr int K  = (MODE == 2) ? 512 : 256;   // reduction dim
    constexpr int CH = (MODE == 2) ? 512 : 256;   // B-matrix channel count
    constexpr int OC = (MODE == 1) ? 512 : 256;   // output channel count

    __shared__ float As[32][128];
    __shared__ float Bs[32][64];

    int tid = threadIdx.x;
    int tx = tid & 15, ty = tid >> 4;
    int gm = blockIdx.x;
    int l0 = blockIdx.y * 64;
    int b  = blockIdx.z;

    // A-load mapping: thread loads row lm, k-range [kg, kg+16)
    int lm = tid & 127;
    int kg = (tid >> 7) << 4;
    int grow;
    if (MODE == 0) grow = (lm < 64) ? (gm * 64 + lm) : (256 + gm * 64 + (lm - 64));
    else           grow = gm * 128 + lm;
    const float* arow = A + (size_t)grow * K + kg;

    // B-load mapping: thread loads rows bk, bk+16, l-range [bl, bl+4)
    int bl = (tid & 15) * 4;
    int bk = tid >> 4;

    float acc[2][4][4] = {};

    for (int k0 = 0; k0 < K; k0 += 32) {
        float4 av[4];
        #pragma unroll
        for (int t = 0; t < 4; ++t) av[t] = *(const float4*)(arow + k0 + t * 4);

        const float* brow0 = Bm + ((size_t)b * CH + k0 + bk) * LL + l0 + bl;
        float4 bv0 = *(const float4*)brow0;
        float4 bv1 = *(const float4*)(brow0 + (size_t)16 * LL);
        if (MODE == 1) {
            int i0 = k0 + bk, i1 = i0 + 16;
            float s0 = bng[i0] * rsqrtf(bnv[i0] + BN_EPS);
            float h0 = fmaf(-bnm[i0], s0, bnb[i0]);
            float s1 = bng[i1] * rsqrtf(bnv[i1] + BN_EPS);
            float h1 = fmaf(-bnm[i1], s1, bnb[i1]);
            bv0.x = fmaf(bv0.x, s0, h0); bv0.y = fmaf(bv0.y, s0, h0);
            bv0.z = fmaf(bv0.z, s0, h0); bv0.w = fmaf(bv0.w, s0, h0);
            bv1.x = fmaf(bv1.x, s1, h1); bv1.y = fmaf(bv1.y, s1, h1);
            bv1.z = fmaf(bv1.z, s1, h1); bv1.w = fmaf(bv1.w, s1, h1);
        }

        __syncthreads();   // WAR: previous iter's readers done before overwrite
        #pragma unroll
        for (int t = 0; t < 4; ++t) {
            As[kg + t * 4 + 0][lm] = av[t].x;
            As[kg + t * 4 + 1][lm] = av[t].y;
            As[kg + t * 4 + 2][lm] = av[t].z;
            As[kg + t * 4 + 3][lm] = av[t].w;
        }
        *(float4*)&Bs[bk][bl]      = bv0;
        *(float4*)&Bs[bk + 16][bl] = bv1;
        __syncthreads();

        #pragma unroll
        for (int kk = 0; kk < 32; ++kk) {
            float4 a0 = *(const float4*)&As[kk][ty * 4];
            float4 a1 = *(const float4*)&As[kk][64 + ty * 4];
            float4 bq = *(const float4*)&Bs[kk][tx * 4];
            float a0v[4] = {a0.x, a0.y, a0.z, a0.w};
            float a1v[4] = {a1.x, a1.y, a1.z, a1.w};
            float bqv[4] = {bq.x, bq.y, bq.z, bq.w};
            #pragma unroll
            for (int rr = 0; rr < 4; ++rr)
                #pragma unroll
                for (int cc = 0; cc < 4; ++cc) {
                    acc[0][rr][cc] = fmaf(a0v[rr], bqv[cc], acc[0][rr][cc]);
                    acc[1][rr][cc] = fmaf(a1v[rr], bqv[cc], acc[1][rr][cc]);
                }
        }
    }

    // epilogue (float4 over the 4 consecutive l's)
    #pragma unroll
    for (int rr = 0; rr < 4; ++rr) {
        if (MODE == 0) {
            int o1 = gm * 64 + ty * 4 + rr;
            size_t oi = ((size_t)b * OC + o1) * LL + l0 + tx * 4;
            float bz1 = bias[o1], bz2 = bias[o1 + 256];
            float4 xr = *(const float4*)(X + oi);
            float4 r;
            r.x = xr.x + (acc[0][rr][0] + bz1) * sigmoidf_(acc[1][rr][0] + bz2);
            r.y = xr.y + (acc[0][rr][1] + bz1) * sigmoidf_(acc[1][rr][1] + bz2);
            r.z = xr.z + (acc[0][rr][2] + bz1) * sigmoidf_(acc[1][rr][2] + bz2);
            r.w = xr.w + (acc[0][rr][3] + bz1) * sigmoidf_(acc[1][rr][3] + bz2);
            *(float4*)(Out + oi) = r;
        } else if (MODE == 1) {
            int o0 = gm * 128 + ty * 4 + rr;
            #pragma unroll
            for (int hf = 0; hf < 2; ++hf) {
                int o = o0 + hf * 64;
                size_t oi = ((size_t)b * OC + o) * LL + l0 + tx * 4;
                float bz = bias[o];
                float4 r;
                r.x = gelu_exact(acc[hf][rr][0] + bz);
                r.y = gelu_exact(acc[hf][rr][1] + bz);
                r.z = gelu_exact(acc[hf][rr][2] + bz);
                r.w = gelu_exact(acc[hf][rr][3] + bz);
                *(float4*)(Out + oi) = r;
            }
        } else {
            int o0 = gm * 128 + ty * 4 + rr;
            #pragma unroll
            for (int hf = 0; hf < 2; ++hf) {
                int o = o0 + hf * 64;
                size_t oi = ((size_t)b * OC + o) * LL + l0 + tx * 4;
                float bz = bias[o];
                float4 xr = *(const float4*)(X + oi);
                float4 r;
                r.x = xr.x + acc[hf][rr][0] + bz;
                r.y = xr.y + acc[hf][rr][1] + bz;
                r.z = xr.z + acc[hf][rr][2] + bz;
                r.w = xr.w + acc[hf][rr][3] + bz;
                *(float4*)(Out + oi) = r;
            }
        }
    }
}

// ---------------------------------------------------------------------------
extern "C" void kernel_launch(void* const* d_in, const int* in_sizes, int n_in,
                              void* d_out, int out_size, void* d_ws, size_t ws_size,
                              hipStream_t stream) {
    const float* x       = (const float*)d_in[0];
    const float* g1      = (const float*)d_in[1];
    const float* b1      = (const float*)d_in[2];
    const float* m1      = (const float*)d_in[3];
    const float* v1      = (const float*)d_in[4];
    const float* log_dt  = (const float*)d_in[5];
    const float* logA_re = (const float*)d_in[6];
    const float* A_im    = (const float*)d_in[7];
    const float* C_re    = (const float*)d_in[8];
    const float* C_im    = (const float*)d_in[9];
    const float* D       = (const float*)d_in[10];
    const float* Wo      = (const float*)d_in[11];
    const float* bo      = (const float*)d_in[12];
    const float* g2      = (const float*)d_in[13];
    const float* b2      = (const float*)d_in[14];
    const float* m2      = (const float*)d_in[15];
    const float* v2      = (const float*)d_in[16];
    const float* W2      = (const float*)d_in[17];
    const float* b2f     = (const float*)d_in[18];
    const float* W3      = (const float*)d_in[19];
    const float* b3      = (const float*)d_in[20];
    float* out = (float*)d_out;

    char* wsb = (char*)d_ws;
    float* yreg = (float*)wsb;                                  // 64 MB: ycomb -> s4y (in place)
    float* h2   = (float*)wsb;                                  // 128 MB during FFN (s4y dead by then)
    float* cst  = (float*)(wsb + (size_t)128 * 1024 * 1024);    // 192 KB constants

    size_t ybytes = (size_t)BB * HH * LL * sizeof(float);
    hipMemsetAsync(yreg, 0, ybytes, stream);

    k_consts<<<dim3(HH * NN2 / 256), dim3(256), 0, stream>>>(log_dt, logA_re, A_im, C_re, C_im, cst);
    k_scan<<<dim3(BB * HH), dim3(64), 0, stream>>>(x, g1, b1, m1, v1, cst, yreg);
    k_combine<<<dim3(BB * HH * LL / 4 / 256), dim3(256), 0, stream>>>(x, g1, b1, m1, v1, D, yreg);
    // residual 1: x1 = x + glu(Wo @ s4y + bo)  -> d_out
    k_gemm<0><<<dim3(4, 64, 16), dim3(256), 0, stream>>>(Wo, yreg, bo, x,
                                                         nullptr, nullptr, nullptr, nullptr, out);
    // FFN hidden: h2 = gelu(W2 @ bn2(x1) + b2f)
    k_gemm<1><<<dim3(4, 64, 16), dim3(256), 0, stream>>>(W2, out, b2f, nullptr,
                                                         g2, b2, m2, v2, h2);
    // final: out = x1 + W3 @ h2 + b3   (in-place elementwise on d_out)
    k_gemm<2><<<dim3(2, 64, 16), dim3(256), 0, stream>>>(W3, h2, b3, out,
                                                         nullptr, nullptr, nullptr, nullptr, out);
}

// Round 4
// 1073.485 us; speedup vs baseline: 1.1152x; 1.1152x over previous
//
#include <hip/hip_runtime.h>

#define BB 16
#define HH 256
#define LL 4096
#define NN2 32

static constexpr float BN_EPS = 1e-5f;

__device__ __forceinline__ float gelu_exact(float v) {
    return 0.5f * v * (1.0f + erff(v * 0.70710678118654752f));
}
__device__ __forceinline__ float sigmoidf_(float v) {
    return 1.0f / (1.0f + expf(-v));
}

// ---------------------------------------------------------------------------
// K0: per-(h,n) SSM constants (unchanged).
// cst layout (each 8192 floats): [0]=w_re [1]=w_im [2]=c0_re [3]=c0_im [4]=c1_re [5]=c1_im
// ---------------------------------------------------------------------------
__global__ void k_consts(const float* __restrict__ log_dt,
                         const float* __restrict__ logA_re,
                         const float* __restrict__ A_im,
                         const float* __restrict__ C_re,
                         const float* __restrict__ C_im,
                         float* __restrict__ cst) {
    int idx = blockIdx.x * blockDim.x + threadIdx.x;
    if (idx >= HH * NN2) return;
    int h = idx / NN2;
    float dt = expf(log_dt[h]);
    float Ar = -expf(logA_re[idx]);
    float Ai = A_im[idx];
    float er = expf(dt * Ar);
    float wr = er * cosf(dt * Ai);
    float wi = er * sinf(dt * Ai);
    float Er = wr - 1.0f, Ei = wi;
    float inv = 1.0f / (Ar * Ar + Ai * Ai);
    float Fr = (Er * Ar + Ei * Ai) * inv;
    float Fi = (Ei * Ar - Er * Ai) * inv;
    cst[idx] = wr;
    cst[8192 + idx] = wi;
    #pragma unroll
    for (int c = 0; c < 2; ++c) {
        float Cr = C_re[c * HH * NN2 + idx], Ci = C_im[c * HH * NN2 + idx];
        cst[8192 * (2 + 2 * c) + idx] = 2.0f * (Cr * Fr - Ci * Fi);
        cst[8192 * (3 + 2 * c) + idx] = 2.0f * (Cr * Fi + Ci * Fr);
    }
}

// ---------------------------------------------------------------------------
// K2: bidirectional diagonal-SSM scan, one wave per (b,h) row.
//  - 1 coalesced global load per chunk (lane n loads its own step's x),
//    software-prefetched one chunk ahead; BN applied once at stage time.
//  - x broadcast to all modes via ds_read_b128 (uniform addr per half).
//  - per-step contributions accumulated 4-at-a-time in regs, written as
//    ds_write_b128 into an XOR-swizzled [mode][36] tile (read side
//    conflict-free; write side uniform bank histogram).
//  - fwd/bwd halves store plain coalesced results to separate buffers
//    (no atomics, no memset).
// LDS map (dwords): [0..1151] fwd contrib [32][36], [1152..2303] bwd contrib,
//                   [2304..2367] x stage (32 fwd + 32 bwd).
// ---------------------------------------------------------------------------
__global__ __launch_bounds__(64) void k_scan(const float* __restrict__ x,
                                             const float* __restrict__ g1,
                                             const float* __restrict__ b1,
                                             const float* __restrict__ m1,
                                             const float* __restrict__ v1,
                                             const float* __restrict__ cst,
                                             float* __restrict__ yf,
                                             float* __restrict__ yb) {
    __shared__ float smem[2368];
    int bh = blockIdx.x;
    int h = bh & (HH - 1);
    int lane = threadIdx.x;
    int half = lane >> 5;
    int n = lane & 31;
    int hn = h * NN2 + n;

    float wr = cst[hn];
    float wi = cst[8192 + hn];
    float Cr = cst[8192 * (2 + 2 * half) + hn];
    float Ci = cst[8192 * (3 + 2 * half) + hn];

    float sc = g1[h] * rsqrtf(v1[h] + BN_EPS);
    float sh = fmaf(-m1[h], sc, b1[h]);

    const float* xrow = x + (size_t)bh * LL;
    float* yfr = yf + (size_t)bh * LL;
    float* ybr = yb + (size_t)bh * LL;

    float sr = 0.0f, si = 0.0f;
    const int hbase = half * 1152;
    const int xsw = (n >> 3) << 2;              // 0,4,8,12 XOR swizzle
    const int lbase = hbase + n * 36;
    const int xbase = 2304 + half * 32;

    // prefetch chunk 0's x element for this lane
    float xraw = half ? xrow[LL - 1 - n] : xrow[n];

    for (int c = 0; c < LL / 32; ++c) {
        smem[xbase + n] = fmaf(xraw, sc, sh);
        if (c + 1 < LL / 32) {
            int gnext = (c + 1) * 32 + n;
            xraw = half ? xrow[LL - 1 - gnext] : xrow[gnext];
        }
        __syncthreads();

        #pragma unroll
        for (int j = 0; j < 32; j += 4) {
            float4 xq = *(const float4*)&smem[xbase + j];
            float4 cb;
            { float t0 = fmaf(wr, sr, xq.x); float ns = fmaf(wi, sr, wr * si);
              sr = fmaf(-wi, si, t0); si = ns; cb.x = fmaf(Cr, sr, -(Ci * si)); }
            { float t0 = fmaf(wr, sr, xq.y); float ns = fmaf(wi, sr, wr * si);
              sr = fmaf(-wi, si, t0); si = ns; cb.y = fmaf(Cr, sr, -(Ci * si)); }
            { float t0 = fmaf(wr, sr, xq.z); float ns = fmaf(wi, sr, wr * si);
              sr = fmaf(-wi, si, t0); si = ns; cb.z = fmaf(Cr, sr, -(Ci * si)); }
            { float t0 = fmaf(wr, sr, xq.w); float ns = fmaf(wi, sr, wr * si);
              sr = fmaf(-wi, si, t0); si = ns; cb.w = fmaf(Cr, sr, -(Ci * si)); }
            *(float4*)&smem[lbase + (j ^ xsw)] = cb;
        }
        __syncthreads();

        // column sum: lane n owns step n; 4 partials for ILP
        float s0 = 0.0f, s1 = 0.0f, s2 = 0.0f, s3 = 0.0f;
        #pragma unroll
        for (int m = 0; m < 32; m += 4) {
            s0 += smem[hbase + (m + 0) * 36 + (n ^ (((m + 0) >> 3) << 2))];
            s1 += smem[hbase + (m + 1) * 36 + (n ^ (((m + 1) >> 3) << 2))];
            s2 += smem[hbase + (m + 2) * 36 + (n ^ (((m + 2) >> 3) << 2))];
            s3 += smem[hbase + (m + 3) * 36 + (n ^ (((m + 3) >> 3) << 2))];
        }
        float sum = (s0 + s1) + (s2 + s3);
        int gl = c * 32 + n;
        if (half) {
            int oidx = LL - 2 - gl;
            if (oidx >= 0) ybr[oidx] = sum;
        } else {
            yfr[gl] = sum;
        }
    }
}

// ---------------------------------------------------------------------------
// K2b: in-place  y <- gelu(y + yb + D[h] * bn1(x)); yb[row][L-1] is invalid
// (never written by the bwd scan) and masked to 0.
// ---------------------------------------------------------------------------
__global__ void k_combine(const float* __restrict__ x,
                          const float* __restrict__ g1,
                          const float* __restrict__ b1,
                          const float* __restrict__ m1,
                          const float* __restrict__ v1,
                          const float* __restrict__ D,
                          const float* __restrict__ yb,
                          float* __restrict__ y) {
    int i4 = blockIdx.x * blockDim.x + threadIdx.x;
    if (i4 >= BB * HH * LL / 4) return;
    int row = i4 >> 10;          // L/4 = 1024 float4 per row
    int h = row & (HH - 1);
    float sc = g1[h] * rsqrtf(v1[h] + BN_EPS);
    float sh = fmaf(-m1[h], sc, b1[h]);
    float d = D[h];
    float4 xv = ((const float4*)x)[i4];
    float4 yv = ((float4*)y)[i4];
    float4 bv = ((const float4*)yb)[i4];
    if ((i4 & 1023) == 1023) bv.w = 0.0f;   // yb[L-1] unwritten
    yv.x = gelu_exact(fmaf(d, fmaf(xv.x, sc, sh), yv.x + bv.x));
    yv.y = gelu_exact(fmaf(d, fmaf(xv.y, sc, sh), yv.y + bv.y));
    yv.z = gelu_exact(fmaf(d, fmaf(xv.z, sc, sh), yv.z + bv.z));
    yv.w = gelu_exact(fmaf(d, fmaf(xv.w, sc, sh), yv.w + bv.w));
    ((float4*)y)[i4] = yv;
}

// ---------------------------------------------------------------------------
// Tiled f32 GEMM (unchanged).
// MODE 0: Out = X + glu(Wo @ Bm + bias)            (Out=d_out, X=x)
// MODE 1: Out = gelu(W2 @ bn2(Bm) + bias)          (Out=h2, Bm=x1)
// MODE 2: Out = X + (W3 @ Bm) + bias               (Out=X=d_out in-place)
// ---------------------------------------------------------------------------
template <int MODE>
__global__ __launch_bounds__(256) void k_gemm(const float* __restrict__ A,
                                              const float* __restrict__ Bm,
                                              const float* __restrict__ bias,
                                              const float* __restrict__ X,
                                              const float* __restrict__ bng,
                                              const float* __restrict__ bnb,
                                              const float* __restrict__ bnm,
                                              const float* __restrict__ bnv,
                                              float* __restrict__ Out) {
    constexpr int K  = (MODE == 2) ? 512 : 256;   // reduction dim
    constexpr int CH = (MODE == 2) ? 512 : 256;   // B-matrix channel count
    constexpr int OC = (MODE == 1) ? 512 : 256;   // output channel count

    __shared__ float As[32][128];
    __shared__ float Bs[32][64];

    int tid = threadIdx.x;
    int tx = tid & 15, ty = tid >> 4;
    int gm = blockIdx.x;
    int l0 = blockIdx.y * 64;
    int b  = blockIdx.z;

    int lm = tid & 127;
    int kg = (tid >> 7) << 4;
    int grow;
    if (MODE == 0) grow = (lm < 64) ? (gm * 64 + lm) : (256 + gm * 64 + (lm - 64));
    else           grow = gm * 128 + lm;
    const float* arow = A + (size_t)grow * K + kg;

    int bl = (tid & 15) * 4;
    int bk = tid >> 4;

    float acc[2][4][4] = {};

    for (int k0 = 0; k0 < K; k0 += 32) {
        float4 av[4];
        #pragma unroll
        for (int t = 0; t < 4; ++t) av[t] = *(const float4*)(arow + k0 + t * 4);

        const float* brow0 = Bm + ((size_t)b * CH + k0 + bk) * LL + l0 + bl;
        float4 bv0 = *(const float4*)brow0;
        float4 bv1 = *(const float4*)(brow0 + (size_t)16 * LL);
        if (MODE == 1) {
            int i0 = k0 + bk, i1 = i0 + 16;
            float s0 = bng[i0] * rsqrtf(bnv[i0] + BN_EPS);
            float h0 = fmaf(-bnm[i0], s0, bnb[i0]);
            float s1 = bng[i1] * rsqrtf(bnv[i1] + BN_EPS);
            float h1 = fmaf(-bnm[i1], s1, bnb[i1]);
            bv0.x = fmaf(bv0.x, s0, h0); bv0.y = fmaf(bv0.y, s0, h0);
            bv0.z = fmaf(bv0.z, s0, h0); bv0.w = fmaf(bv0.w, s0, h0);
            bv1.x = fmaf(bv1.x, s1, h1); bv1.y = fmaf(bv1.y, s1, h1);
            bv1.z = fmaf(bv1.z, s1, h1); bv1.w = fmaf(bv1.w, s1, h1);
        }

        __syncthreads();   // WAR: previous iter's readers done before overwrite
        #pragma unroll
        for (int t = 0; t < 4; ++t) {
            As[kg + t * 4 + 0][lm] = av[t].x;
            As[kg + t * 4 + 1][lm] = av[t].y;
            As[kg + t * 4 + 2][lm] = av[t].z;
            As[kg + t * 4 + 3][lm] = av[t].w;
        }
        *(float4*)&Bs[bk][bl]      = bv0;
        *(float4*)&Bs[bk + 16][bl] = bv1;
        __syncthreads();

        #pragma unroll
        for (int kk = 0; kk < 32; ++kk) {
            float4 a0 = *(const float4*)&As[kk][ty * 4];
            float4 a1 = *(const float4*)&As[kk][64 + ty * 4];
            float4 bq = *(const float4*)&Bs[kk][tx * 4];
            float a0v[4] = {a0.x, a0.y, a0.z, a0.w};
            float a1v[4] = {a1.x, a1.y, a1.z, a1.w};
            float bqv[4] = {bq.x, bq.y, bq.z, bq.w};
            #pragma unroll
            for (int rr = 0; rr < 4; ++rr)
                #pragma unroll
                for (int cc = 0; cc < 4; ++cc) {
                    acc[0][rr][cc] = fmaf(a0v[rr], bqv[cc], acc[0][rr][cc]);
                    acc[1][rr][cc] = fmaf(a1v[rr], bqv[cc], acc[1][rr][cc]);
                }
        }
    }

    #pragma unroll
    for (int rr = 0; rr < 4; ++rr) {
        if (MODE == 0) {
            int o1 = gm * 64 + ty * 4 + rr;
            size_t oi = ((size_t)b * OC + o1) * LL + l0 + tx * 4;
            float bz1 = bias[o1], bz2 = bias[o1 + 256];
            float4 xr = *(const float4*)(X + oi);
            float4 r;
            r.x = xr.x + (acc[0][rr][0] + bz1) * sigmoidf_(acc[1][rr][0] + bz2);
            r.y = xr.y + (acc[0][rr][1] + bz1) * sigmoidf_(acc[1][rr][1] + bz2);
            r.z = xr.z + (acc[0][rr][2] + bz1) * sigmoidf_(acc[1][rr][2] + bz2);
            r.w = xr.w + (acc[0][rr][3] + bz1) * sigmoidf_(acc[1][rr][3] + bz2);
            *(float4*)(Out + oi) = r;
        } else if (MODE == 1) {
            int o0 = gm * 128 + ty * 4 + rr;
            #pragma unroll
            for (int hf = 0; hf < 2; ++hf) {
                int o = o0 + hf * 64;
                size_t oi = ((size_t)b * OC + o) * LL + l0 + tx * 4;
                float bz = bias[o];
                float4 r;
                r.x = gelu_exact(acc[hf][rr][0] + bz);
                r.y = gelu_exact(acc[hf][rr][1] + bz);
                r.z = gelu_exact(acc[hf][rr][2] + bz);
                r.w = gelu_exact(acc[hf][rr][3] + bz);
                *(float4*)(Out + oi) = r;
            }
        } else {
            int o0 = gm * 128 + ty * 4 + rr;
            #pragma unroll
            for (int hf = 0; hf < 2; ++hf) {
                int o = o0 + hf * 64;
                size_t oi = ((size_t)b * OC + o) * LL + l0 + tx * 4;
                float bz = bias[o];
                float4 xr = *(const float4*)(X + oi);
                float4 r;
                r.x = xr.x + acc[hf][rr][0] + bz;
                r.y = xr.y + acc[hf][rr][1] + bz;
                r.z = xr.z + acc[hf][rr][2] + bz;
                r.w = xr.w + acc[hf][rr][3] + bz;
                *(float4*)(Out + oi) = r;
            }
        }
    }
}

// ---------------------------------------------------------------------------
extern "C" void kernel_launch(void* const* d_in, const int* in_sizes, int n_in,
                              void* d_out, int out_size, void* d_ws, size_t ws_size,
                              hipStream_t stream) {
    const float* x       = (const float*)d_in[0];
    const float* g1      = (const float*)d_in[1];
    const float* b1      = (const float*)d_in[2];
    const float* m1      = (const float*)d_in[3];
    const float* v1      = (const float*)d_in[4];
    const float* log_dt  = (const float*)d_in[5];
    const float* logA_re = (const float*)d_in[6];
    const float* A_im    = (const float*)d_in[7];
    const float* C_re    = (const float*)d_in[8];
    const float* C_im    = (const float*)d_in[9];
    const float* D       = (const float*)d_in[10];
    const float* Wo      = (const float*)d_in[11];
    const float* bo      = (const float*)d_in[12];
    const float* g2      = (const float*)d_in[13];
    const float* b2      = (const float*)d_in[14];
    const float* m2      = (const float*)d_in[15];
    const float* v2      = (const float*)d_in[16];
    const float* W2      = (const float*)d_in[17];
    const float* b2f     = (const float*)d_in[18];
    const float* W3      = (const float*)d_in[19];
    const float* b3      = (const float*)d_in[20];
    float* out = (float*)d_out;

    char* wsb = (char*)d_ws;
    float* yf   = (float*)wsb;                                  //   0..64 MB: fwd scan -> combined s4y
    float* yb   = (float*)(wsb + (size_t)64 * 1024 * 1024);     //  64..128 MB: bwd scan (dead after combine)
    float* h2   = (float*)wsb;                                  //   0..128 MB during FFN (yf/yb dead)
    float* cst  = (float*)(wsb + (size_t)128 * 1024 * 1024);    // 128 MB+: constants (192 KB)

    k_consts<<<dim3(HH * NN2 / 256), dim3(256), 0, stream>>>(log_dt, logA_re, A_im, C_re, C_im, cst);
    k_scan<<<dim3(BB * HH), dim3(64), 0, stream>>>(x, g1, b1, m1, v1, cst, yf, yb);
    k_combine<<<dim3(BB * HH * LL / 4 / 256), dim3(256), 0, stream>>>(x, g1, b1, m1, v1, D, yb, yf);
    // residual 1: x1 = x + glu(Wo @ s4y + bo)  -> d_out
    k_gemm<0><<<dim3(4, 64, 16), dim3(256), 0, stream>>>(Wo, yf, bo, x,
                                                         nullptr, nullptr, nullptr, nullptr, out);
    // FFN hidden: h2 = gelu(W2 @ bn2(x1) + b2f)
    k_gemm<1><<<dim3(4, 64, 16), dim3(256), 0, stream>>>(W2, out, b2f, nullptr,
                                                         g2, b2, m2, v2, h2);
    // final: out = x1 + W3 @ h2 + b3   (in-place elementwise on d_out)
    k_gemm<2><<<dim3(2, 64, 16), dim3(256), 0, stream>>>(W3, h2, b3, out,
                                                         nullptr, nullptr, nullptr, nullptr, out);
}

// Round 7
// 982.137 us; speedup vs baseline: 1.2189x; 1.0930x over previous
//
#include <hip/hip_runtime.h>

#define BB 16
#define HH 256
#define LL 4096
#define NN2 32

using f32x16 = __attribute__((ext_vector_type(16))) float;
using bfx8   = __attribute__((ext_vector_type(8))) short;

static constexpr float BN_EPS = 1e-5f;

__device__ __forceinline__ float gelu_exact(float v) {
    return 0.5f * v * (1.0f + erff(v * 0.70710678118654752f));
}
__device__ __forceinline__ float sigmoidf_(float v) {
    return 1.0f / (1.0f + expf(-v));
}
// f32 -> bf16 (RNE) and back, via bit ops (no header type dependencies)
__device__ __forceinline__ ushort f2bf(float f) {
    uint u = __float_as_uint(f);
    u += 0x7fffu + ((u >> 16) & 1u);
    return (ushort)(u >> 16);
}
__device__ __forceinline__ float bf2f(ushort h) {
    return __uint_as_float(((uint)h) << 16);
}
// LDS B-tile addressing: row l = 12l + 4*((l>>3)&7) + 32*(l>>6).
// (The last term fixes the round-5 bug: without it the +4/group swizzle wraps
// at l=64 and rows 62..63 overlap rows 64..65. Max addr 1591 < 1600/plane.)
__device__ __forceinline__ int rowstart(int l) {
    return l * 12 + ((l >> 3) & 7) * 4 + ((l >> 6) << 5);
}

// ---------------------------------------------------------------------------
// K0: per-(h,n) SSM constants (validated, unchanged).
// ---------------------------------------------------------------------------
__global__ void k_consts(const float* __restrict__ log_dt,
                         const float* __restrict__ logA_re,
                         const float* __restrict__ A_im,
                         const float* __restrict__ C_re,
                         const float* __restrict__ C_im,
                         float* __restrict__ cst) {
    int idx = blockIdx.x * blockDim.x + threadIdx.x;
    if (idx >= HH * NN2) return;
    int h = idx / NN2;
    float dt = expf(log_dt[h]);
    float Ar = -expf(logA_re[idx]);
    float Ai = A_im[idx];
    float er = expf(dt * Ar);
    float wr = er * cosf(dt * Ai);
    float wi = er * sinf(dt * Ai);
    float Er = wr - 1.0f, Ei = wi;
    float inv = 1.0f / (Ar * Ar + Ai * Ai);
    float Fr = (Er * Ar + Ei * Ai) * inv;
    float Fi = (Ei * Ar - Er * Ai) * inv;
    cst[idx] = wr;
    cst[8192 + idx] = wi;
    #pragma unroll
    for (int c = 0; c < 2; ++c) {
        float Cr = C_re[c * HH * NN2 + idx], Ci = C_im[c * HH * NN2 + idx];
        cst[8192 * (2 + 2 * c) + idx] = 2.0f * (Cr * Fr - Ci * Fi);
        cst[8192 * (3 + 2 * c) + idx] = 2.0f * (Cr * Fi + Ci * Fr);
    }
}

// ---------------------------------------------------------------------------
// Small preps for the MFMA path: BN2 fold + weight split.
// ---------------------------------------------------------------------------
__global__ void k_prep2a(const float* __restrict__ g2, const float* __restrict__ b2,
                         const float* __restrict__ m2, const float* __restrict__ v2,
                         float* __restrict__ s2, float* __restrict__ t2) {
    int k = threadIdx.x;  // 256
    float s = g2[k] * rsqrtf(v2[k] + BN_EPS);
    s2[k] = s;
    t2[k] = fmaf(-m2[k], s, b2[k]);
}
__global__ void k_prep2b(const float* __restrict__ W2, const float* __restrict__ t2,
                         const float* __restrict__ b2f, float* __restrict__ bias2p) {
    int o = blockIdx.x * 256 + threadIdx.x;  // 512
    float acc = b2f[o];
    for (int k = 0; k < 256; ++k) acc = fmaf(W2[o * 256 + k], t2[k], acc);
    bias2p[o] = acc;
}
__global__ void k_wprep(const float* __restrict__ Wo, const float* __restrict__ W2,
                        const float* __restrict__ W3, const float* __restrict__ s2,
                        ushort* __restrict__ WoH, ushort* __restrict__ WoL,
                        ushort* __restrict__ W2H, ushort* __restrict__ W2L,
                        ushort* __restrict__ W3H, ushort* __restrict__ W3L) {
    int i = blockIdx.x * 256 + threadIdx.x;  // 3 * 131072
    int job = i >> 17, e = i & 131071;
    float w; ushort *H, *L;
    if (job == 0)      { w = Wo[e];                  H = WoH; L = WoL; }
    else if (job == 1) { w = W2[e] * s2[e & 255];    H = W2H; L = W2L; }
    else               { w = W3[e];                  H = W3H; L = W3L; }
    ushort h = f2bf(w);
    H[e] = h;
    L[e] = f2bf(w - bf2f(h));
}

// ---------------------------------------------------------------------------
// K2: bidirectional diagonal-SSM scan (validated round-4 version, unchanged).
// ---------------------------------------------------------------------------
__global__ __launch_bounds__(64) void k_scan(const float* __restrict__ x,
                                             const float* __restrict__ g1,
                                             const float* __restrict__ b1,
                                             const float* __restrict__ m1,
                                             const float* __restrict__ v1,
                                             const float* __restrict__ cst,
                                             float* __restrict__ yf,
                                             float* __restrict__ yb) {
    __shared__ float smem[2368];
    int bh = blockIdx.x;
    int h = bh & (HH - 1);
    int lane = threadIdx.x;
    int half = lane >> 5;
    int n = lane & 31;
    int hn = h * NN2 + n;

    float wr = cst[hn];
    float wi = cst[8192 + hn];
    float Cr = cst[8192 * (2 + 2 * half) + hn];
    float Ci = cst[8192 * (3 + 2 * half) + hn];

    float sc = g1[h] * rsqrtf(v1[h] + BN_EPS);
    float sh = fmaf(-m1[h], sc, b1[h]);

    const float* xrow = x + (size_t)bh * LL;
    float* yfr = yf + (size_t)bh * LL;
    float* ybr = yb + (size_t)bh * LL;

    float sr = 0.0f, si = 0.0f;
    const int hbase = half * 1152;
    const int xsw = (n >> 3) << 2;
    const int lbase = hbase + n * 36;
    const int xbase = 2304 + half * 32;

    float xraw = half ? xrow[LL - 1 - n] : xrow[n];

    for (int c = 0; c < LL / 32; ++c) {
        smem[xbase + n] = fmaf(xraw, sc, sh);
        if (c + 1 < LL / 32) {
            int gnext = (c + 1) * 32 + n;
            xraw = half ? xrow[LL - 1 - gnext] : xrow[gnext];
        }
        __syncthreads();

        #pragma unroll
        for (int j = 0; j < 32; j += 4) {
            float4 xq = *(const float4*)&smem[xbase + j];
            float4 cb;
            { float t0 = fmaf(wr, sr, xq.x); float ns = fmaf(wi, sr, wr * si);
              sr = fmaf(-wi, si, t0); si = ns; cb.x = fmaf(Cr, sr, -(Ci * si)); }
            { float t0 = fmaf(wr, sr, xq.y); float ns = fmaf(wi, sr, wr * si);
              sr = fmaf(-wi, si, t0); si = ns; cb.y = fmaf(Cr, sr, -(Ci * si)); }
            { float t0 = fmaf(wr, sr, xq.z); float ns = fmaf(wi, sr, wr * si);
              sr = fmaf(-wi, si, t0); si = ns; cb.z = fmaf(Cr, sr, -(Ci * si)); }
            { float t0 = fmaf(wr, sr, xq.w); float ns = fmaf(wi, sr, wr * si);
              sr = fmaf(-wi, si, t0); si = ns; cb.w = fmaf(Cr, sr, -(Ci * si)); }
            *(float4*)&smem[lbase + (j ^ xsw)] = cb;
        }
        __syncthreads();

        float s0 = 0.0f, s1 = 0.0f, s2 = 0.0f, s3 = 0.0f;
        #pragma unroll
        for (int m = 0; m < 32; m += 4) {
            s0 += smem[hbase + (m + 0) * 36 + (n ^ (((m + 0) >> 3) << 2))];
            s1 += smem[hbase + (m + 1) * 36 + (n ^ (((m + 1) >> 3) << 2))];
            s2 += smem[hbase + (m + 2) * 36 + (n ^ (((m + 2) >> 3) << 2))];
            s3 += smem[hbase + (m + 3) * 36 + (n ^ (((m + 3) >> 3) << 2))];
        }
        float sum = (s0 + s1) + (s2 + s3);
        int gl = c * 32 + n;
        if (half) {
            int oidx = LL - 2 - gl;
            if (oidx >= 0) ybr[oidx] = sum;
        } else {
            yfr[gl] = sum;
        }
    }
}

// ---------------------------------------------------------------------------
// K2b (fallback): in-place f32 combine (validated, unchanged).
// ---------------------------------------------------------------------------
__global__ void k_combine(const float* __restrict__ x,
                          const float* __restrict__ g1, const float* __restrict__ b1,
                          const float* __restrict__ m1, const float* __restrict__ v1,
                          const float* __restrict__ D,
                          const float* __restrict__ yb, float* __restrict__ y) {
    int i4 = blockIdx.x * blockDim.x + threadIdx.x;
    if (i4 >= BB * HH * LL / 4) return;
    int row = i4 >> 10;
    int h = row & (HH - 1);
    float sc = g1[h] * rsqrtf(v1[h] + BN_EPS);
    float sh = fmaf(-m1[h], sc, b1[h]);
    float d = D[h];
    float4 xv = ((const float4*)x)[i4];
    float4 yv = ((float4*)y)[i4];
    float4 bv = ((const float4*)yb)[i4];
    if ((i4 & 1023) == 1023) bv.w = 0.0f;
    yv.x = gelu_exact(fmaf(d, fmaf(xv.x, sc, sh), yv.x + bv.x));
    yv.y = gelu_exact(fmaf(d, fmaf(xv.y, sc, sh), yv.y + bv.y));
    yv.z = gelu_exact(fmaf(d, fmaf(xv.z, sc, sh), yv.z + bv.z));
    yv.w = gelu_exact(fmaf(d, fmaf(xv.w, sc, sh), yv.w + bv.w));
    ((float4*)y)[i4] = yv;
}

// ---------------------------------------------------------------------------
// K2b' (primary): combine -> split-bf16 planes s4h/s4l (In of GEMM0).
// ---------------------------------------------------------------------------
__global__ void k_combine2(const float* __restrict__ x,
                           const float* __restrict__ g1, const float* __restrict__ b1,
                           const float* __restrict__ m1, const float* __restrict__ v1,
                           const float* __restrict__ D,
                           const float* __restrict__ yf, const float* __restrict__ yb,
                           ushort* __restrict__ s4h, ushort* __restrict__ s4l) {
    int i4 = blockIdx.x * blockDim.x + threadIdx.x;
    if (i4 >= BB * HH * LL / 4) return;
    int row = i4 >> 10;
    int h = row & (HH - 1);
    float sc = g1[h] * rsqrtf(v1[h] + BN_EPS);
    float sh = fmaf(-m1[h], sc, b1[h]);
    float d = D[h];
    float4 xv = ((const float4*)x)[i4];
    float4 fv = ((const float4*)yf)[i4];
    float4 bv = ((const float4*)yb)[i4];
    if ((i4 & 1023) == 1023) bv.w = 0.0f;   // yb[L-1] unwritten
    float v0 = gelu_exact(fmaf(d, fmaf(xv.x, sc, sh), fv.x + bv.x));
    float v1_ = gelu_exact(fmaf(d, fmaf(xv.y, sc, sh), fv.y + bv.y));
    float v2 = gelu_exact(fmaf(d, fmaf(xv.z, sc, sh), fv.z + bv.z));
    float v3 = gelu_exact(fmaf(d, fmaf(xv.w, sc, sh), fv.w + bv.w));
    ushort4 hh, ll;
    hh.x = f2bf(v0);  ll.x = f2bf(v0 - bf2f(hh.x));
    hh.y = f2bf(v1_); ll.y = f2bf(v1_ - bf2f(hh.y));
    hh.z = f2bf(v2);  ll.z = f2bf(v2 - bf2f(hh.z));
    hh.w = f2bf(v3);  ll.w = f2bf(v3 - bf2f(hh.w));
    ((ushort4*)s4h)[i4] = hh;
    ((ushort4*)s4l)[i4] = ll;
}

// ---------------------------------------------------------------------------
// Split-bf16 MFMA GEMM. Block = 4 waves, tile 128o x 128l, K-chunk 16.
// A (weight planes, [OC][K] bf16) loaded global->reg (L2-resident).
// B (activation planes, [B][K][L] bf16) staged to LDS with k-pair transpose:
//   BT[l][kp] dword = (bf16 k=2kp, bf16 k=2kp+1), base rowstart(l),
//   slot = (kp&3) + 4*((kp>>2) ^ (l&1))  -> frag read = 1 aligned b128 / plane.
// Per k-chunk per wave: 4 n-frags x 3 split-MFMAs (v_mfma_f32_32x32x16_bf16).
// MODE 0: z = Wo@s4 + bo; GLU via LDS gate exchange; x1 = x + glu ->
//         d_out (f32) + x1h/x1l planes.
// MODE 1: h2 = gelu(W2s@x1 + bias2p) -> h2h/h2l planes.
// MODE 2: d_out += W3@h2 + b3 (in-place, K=512).
// ---------------------------------------------------------------------------
template <int MODE>
__global__ __launch_bounds__(256) void k_mgemm(
    const ushort* __restrict__ Ah, const ushort* __restrict__ Al,
    const ushort* __restrict__ Bh, const ushort* __restrict__ Bl,
    const float* __restrict__ bias,
    const float* __restrict__ X,
    float* __restrict__ Outf,
    ushort* __restrict__ Oh, ushort* __restrict__ Ol) {

    constexpr int K  = (MODE == 2) ? 512 : 256;
    constexpr int NK = K / 16;

    __shared__ uint bt[3200];                               // 2 planes x 1600 dw
    __shared__ float gatebuf[(MODE == 0) ? 8192 : 4];       // 32 KiB gate tile (mode 0)

    const int tid  = threadIdx.x;
    const int lane = tid & 63;
    const int w    = tid >> 6;        // wave 0..3
    const int c31  = lane & 31;
    const int g    = lane >> 5;       // k-half selector
    const int gm   = blockIdx.x;
    const int l0   = blockIdx.y * 128;
    const int b    = blockIdx.z;

    // A row (m = c31 within this wave's 32-row band)
    int r = w * 32 + c31;
    int arow;
    if (MODE == 0) arow = (r < 64) ? (gm * 64 + r) : (256 + gm * 64 + (r - 64));
    else           arow = gm * 128 + r;
    const ushort* apH = Ah + (size_t)arow * K;
    const ushort* apL = Al + (size_t)arow * K;

    // B staging map: 128 threads per plane
    const int pl = tid >> 7;
    const int tt = tid & 127;
    const int kp = tt & 7;            // k-pair 0..7 (k = 2kp, 2kp+1)
    const int lg = tt >> 3;           // l-group 0..15 (8 l each)
    const ushort* bplane = pl ? Bl : Bh;
    const ushort* bbase = bplane + ((size_t)b * K + 2 * kp) * LL + l0 + lg * 8;
    uint* btp = bt + pl * 1600;
    const int wb = 96 * lg + 4 * (lg & 7) + 32 * (lg >> 3);   // rowstart(lg*8)
    const int sl0 = (kp & 3) + 4 * (kp >> 2);       // slot for even l
    const int sl1 = (kp & 3) + 4 * ((kp >> 2) ^ 1); // slot for odd l

    f32x16 acc[4];
    #pragma unroll
    for (int f = 0; f < 4; ++f)
        #pragma unroll
        for (int e = 0; e < 16; ++e) acc[f][e] = 0.0f;

    // preload B regs for kc = 0
    uint4 r0 = *(const uint4*)(bbase);
    uint4 r1 = *(const uint4*)(bbase + LL);

    for (int kc = 0; kc < NK; ++kc) {
        __syncthreads();   // WAR: previous chunk's readers done
        // k-pair transpose write: 8 dwords (pairs of the two rows)
        {
            uint p0 = (r0.x & 0xffffu) | (r1.x << 16);
            uint p1 = (r0.x >> 16)     | (r1.x & 0xffff0000u);
            uint p2 = (r0.y & 0xffffu) | (r1.y << 16);
            uint p3 = (r0.y >> 16)     | (r1.y & 0xffff0000u);
            uint p4 = (r0.z & 0xffffu) | (r1.z << 16);
            uint p5 = (r0.z >> 16)     | (r1.z & 0xffff0000u);
            uint p6 = (r0.w & 0xffffu) | (r1.w << 16);
            uint p7 = (r0.w >> 16)     | (r1.w & 0xffff0000u);
            btp[wb +  0 + sl0] = p0;
            btp[wb + 12 + sl1] = p1;
            btp[wb + 24 + sl0] = p2;
            btp[wb + 36 + sl1] = p3;
            btp[wb + 48 + sl0] = p4;
            btp[wb + 60 + sl1] = p5;
            btp[wb + 72 + sl0] = p6;
            btp[wb + 84 + sl1] = p7;
        }
        __syncthreads();
        // prefetch next chunk's B rows
        if (kc + 1 < NK) {
            const ushort* nb = bbase + (size_t)((kc + 1) * 16) * LL;
            r0 = *(const uint4*)(nb);
            r1 = *(const uint4*)(nb + LL);
        }
        // A fragments (direct from global planes)
        bfx8 ah = *(const bfx8*)(apH + kc * 16 + 8 * g);
        bfx8 al = *(const bfx8*)(apL + kc * 16 + 8 * g);
        // B fragments + 3-way split MFMA
        #pragma unroll
        for (int f = 0; f < 4; ++f) {
            int l = f * 32 + c31;
            int ra = rowstart(l) + ((g ^ (l & 1)) << 2);
            bfx8 bhf = *(const bfx8*)(bt + ra);
            bfx8 blf = *(const bfx8*)(bt + 1600 + ra);
            acc[f] = __builtin_amdgcn_mfma_f32_32x32x16_bf16(ah, bhf, acc[f], 0, 0, 0);
            acc[f] = __builtin_amdgcn_mfma_f32_32x32x16_bf16(ah, blf, acc[f], 0, 0, 0);
            acc[f] = __builtin_amdgcn_mfma_f32_32x32x16_bf16(al, bhf, acc[f], 0, 0, 0);
        }
    }

    // ------------------------------ epilogue ------------------------------
    if (MODE == 0) {
        if (w >= 2) {   // gate waves: sigmoid -> LDS
            int grow_base = (w - 2) * 32;
            int og_base = 256 + gm * 64 + grow_base;
            #pragma unroll
            for (int f = 0; f < 4; ++f)
                #pragma unroll
                for (int reg = 0; reg < 16; ++reg) {
                    int rr = (reg & 3) + 8 * (reg >> 2) + 4 * g;
                    float zg = acc[f][reg] + bias[og_base + rr];
                    gatebuf[(grow_base + rr) * 128 + f * 32 + c31] = sigmoidf_(zg);
                }
        }
        __syncthreads();
        if (w < 2) {    // value waves: GLU + residual + stores
            int vr_base = w * 32;
            #pragma unroll
            for (int f = 0; f < 4; ++f)
                #pragma unroll
                for (int reg = 0; reg < 16; ++reg) {
                    int rr = (reg & 3) + 8 * (reg >> 2) + 4 * g;
                    int vr = vr_base + rr;
                    int ov = gm * 64 + vr;
                    size_t oi = ((size_t)b * HH + ov) * LL + l0 + f * 32 + c31;
                    float zv = acc[f][reg] + bias[ov];
                    float res = X[oi] + zv * gatebuf[vr * 128 + f * 32 + c31];
                    Outf[oi] = res;
                    ushort hh = f2bf(res);
                    Oh[oi] = hh;
                    Ol[oi] = f2bf(res - bf2f(hh));
                }
        }
    } else if (MODE == 1) {
        #pragma unroll
        for (int f = 0; f < 4; ++f)
            #pragma unroll
            for (int reg = 0; reg < 16; ++reg) {
                int rr = (reg & 3) + 8 * (reg >> 2) + 4 * g;
                int o = gm * 128 + w * 32 + rr;
                size_t oi = ((size_t)b * 512 + o) * LL + l0 + f * 32 + c31;
                float v = gelu_exact(acc[f][reg] + bias[o]);
                ushort hh = f2bf(v);
                Oh[oi] = hh;
                Ol[oi] = f2bf(v - bf2f(hh));
            }
    } else {
        #pragma unroll
        for (int f = 0; f < 4; ++f)
            #pragma unroll
            for (int reg = 0; reg < 16; ++reg) {
                int rr = (reg & 3) + 8 * (reg >> 2) + 4 * g;
                int o = gm * 128 + w * 32 + rr;
                size_t oi = ((size_t)b * HH + o) * LL + l0 + f * 32 + c31;
                Outf[oi] = Outf[oi] + acc[f][reg] + bias[o];
            }
    }
}

// ---------------------------------------------------------------------------
// Fallback f32 tiled GEMM (validated round-4 version, unchanged).
// ---------------------------------------------------------------------------
template <int MODE>
__global__ __launch_bounds__(256) void k_gemm(const float* __restrict__ A,
                                              const float* __restrict__ Bm,
                                              const float* __restrict__ bias,
                                              const float* __restrict__ X,
                                              const float* __restrict__ bng,
                                              const float* __restrict__ bnb,
                                              const float* __restrict__ bnm,
                                              const float* __restrict__ bnv,
                                              float* __restrict__ Out) {
    constexpr int K  = (MODE == 2) ? 512 : 256;
    constexpr int CH = (MODE == 2) ? 512 : 256;
    constexpr int OC = (MODE == 1) ? 512 : 256;

    __shared__ float As[32][128];
    __shared__ float Bs[32][64];

    int tid = threadIdx.x;
    int tx = tid & 15, ty = tid >> 4;
    int gm = blockIdx.x;
    int l0 = blockIdx.y * 64;
    int b  = blockIdx.z;

    int lm = tid & 127;
    int kg = (tid >> 7) << 4;
    int grow;
    if (MODE == 0) grow = (lm < 64) ? (gm * 64 + lm) : (256 + gm * 64 + (lm - 64));
    else           grow = gm * 128 + lm;
    const float* arow = A + (size_t)grow * K + kg;

    int bl = (tid & 15) * 4;
    int bk = tid >> 4;

    float acc[2][4][4] = {};

    for (int k0 = 0; k0 < K; k0 += 32) {
        float4 av[4];
        #pragma unroll
        for (int t = 0; t < 4; ++t) av[t] = *(const float4*)(arow + k0 + t * 4);

        const float* brow0 = Bm + ((size_t)b * CH + k0 + bk) * LL + l0 + bl;
        float4 bv0 = *(const float4*)brow0;
        float4 bv1 = *(const float4*)(brow0 + (size_t)16 * LL);
        if (MODE == 1) {
            int i0 = k0 + bk, i1 = i0 + 16;
            float s0 = bng[i0] * rsqrtf(bnv[i0] + BN_EPS);
            float h0 = fmaf(-bnm[i0], s0, bnb[i0]);
            float s1 = bng[i1] * rsqrtf(bnv[i1] + BN_EPS);
            float h1 = fmaf(-bnm[i1], s1, bnb[i1]);
            bv0.x = fmaf(bv0.x, s0, h0); bv0.y = fmaf(bv0.y, s0, h0);
            bv0.z = fmaf(bv0.z, s0, h0); bv0.w = fmaf(bv0.w, s0, h0);
            bv1.x = fmaf(bv1.x, s1, h1); bv1.y = fmaf(bv1.y, s1, h1);
            bv1.z = fmaf(bv1.z, s1, h1); bv1.w = fmaf(bv1.w, s1, h1);
        }

        __syncthreads();
        #pragma unroll
        for (int t = 0; t < 4; ++t) {
            As[kg + t * 4 + 0][lm] = av[t].x;
            As[kg + t * 4 + 1][lm] = av[t].y;
            As[kg + t * 4 + 2][lm] = av[t].z;
            As[kg + t * 4 + 3][lm] = av[t].w;
        }
        *(float4*)&Bs[bk][bl]      = bv0;
        *(float4*)&Bs[bk + 16][bl] = bv1;
        __syncthreads();

        #pragma unroll
        for (int kk = 0; kk < 32; ++kk) {
            float4 a0 = *(const float4*)&As[kk][ty * 4];
            float4 a1 = *(const float4*)&As[kk][64 + ty * 4];
            float4 bq = *(const float4*)&Bs[kk][tx * 4];
            float a0v[4] = {a0.x, a0.y, a0.z, a0.w};
            float a1v[4] = {a1.x, a1.y, a1.z, a1.w};
            float bqv[4] = {bq.x, bq.y, bq.z, bq.w};
            #pragma unroll
            for (int rr = 0; rr < 4; ++rr)
                #pragma unroll
                for (int cc = 0; cc < 4; ++cc) {
                    acc[0][rr][cc] = fmaf(a0v[rr], bqv[cc], acc[0][rr][cc]);
                    acc[1][rr][cc] = fmaf(a1v[rr], bqv[cc], acc[1][rr][cc]);
                }
        }
    }

    #pragma unroll
    for (int rr = 0; rr < 4; ++rr) {
        if (MODE == 0) {
            int o1 = gm * 64 + ty * 4 + rr;
            size_t oi = ((size_t)b * OC + o1) * LL + l0 + tx * 4;
            float bz1 = bias[o1], bz2 = bias[o1 + 256];
            float4 xr = *(const float4*)(X + oi);
            float4 rv;
            rv.x = xr.x + (acc[0][rr][0] + bz1) * sigmoidf_(acc[1][rr][0] + bz2);
            rv.y = xr.y + (acc[0][rr][1] + bz1) * sigmoidf_(acc[1][rr][1] + bz2);
            rv.z = xr.z + (acc[0][rr][2] + bz1) * sigmoidf_(acc[1][rr][2] + bz2);
            rv.w = xr.w + (acc[0][rr][3] + bz1) * sigmoidf_(acc[1][rr][3] + bz2);
            *(float4*)(Out + oi) = rv;
        } else if (MODE == 1) {
            int o0 = gm * 128 + ty * 4 + rr;
            #pragma unroll
            for (int hf = 0; hf < 2; ++hf) {
                int o = o0 + hf * 64;
                size_t oi = ((size_t)b * OC + o) * LL + l0 + tx * 4;
                float bz = bias[o];
                float4 rv;
                rv.x = gelu_exact(acc[hf][rr][0] + bz);
                rv.y = gelu_exact(acc[hf][rr][1] + bz);
                rv.z = gelu_exact(acc[hf][rr][2] + bz);
                rv.w = gelu_exact(acc[hf][rr][3] + bz);
                *(float4*)(Out + oi) = rv;
            }
        } else {
            int o0 = gm * 128 + ty * 4 + rr;
            #pragma unroll
            for (int hf = 0; hf < 2; ++hf) {
                int o = o0 + hf * 64;
                size_t oi = ((size_t)b * OC + o) * LL + l0 + tx * 4;
                float bz = bias[o];
                float4 xr = *(const float4*)(X + oi);
                float4 rv;
                rv.x = xr.x + acc[hf][rr][0] + bz;
                rv.y = xr.y + acc[hf][rr][1] + bz;
                rv.z = xr.z + acc[hf][rr][2] + bz;
                rv.w = xr.w + acc[hf][rr][3] + bz;
                *(float4*)(Out + oi) = rv;
            }
        }
    }
}

// ---------------------------------------------------------------------------
extern "C" void kernel_launch(void* const* d_in, const int* in_sizes, int n_in,
                              void* d_out, int out_size, void* d_ws, size_t ws_size,
                              hipStream_t stream) {
    const float* x       = (const float*)d_in[0];
    const float* g1      = (const float*)d_in[1];
    const float* b1      = (const float*)d_in[2];
    const float* m1      = (const float*)d_in[3];
    const float* v1      = (const float*)d_in[4];
    const float* log_dt  = (const float*)d_in[5];
    const float* logA_re = (const float*)d_in[6];
    const float* A_im    = (const float*)d_in[7];
    const float* C_re    = (const float*)d_in[8];
    const float* C_im    = (const float*)d_in[9];
    const float* D       = (const float*)d_in[10];
    const float* Wo      = (const float*)d_in[11];
    const float* bo      = (const float*)d_in[12];
    const float* g2      = (const float*)d_in[13];
    const float* b2      = (const float*)d_in[14];
    const float* m2      = (const float*)d_in[15];
    const float* v2      = (const float*)d_in[16];
    const float* W2      = (const float*)d_in[17];
    const float* b2f     = (const float*)d_in[18];
    const float* W3      = (const float*)d_in[19];
    const float* b3      = (const float*)d_in[20];
    float* out = (float*)d_out;
    char* wsb = (char*)d_ws;

    const size_t MB = 1024 * 1024;
    const size_t NEEDED = 194 * MB;

    if (ws_size >= NEEDED) {
        // -------- primary: split-bf16 MFMA pipeline --------
        float*  cst    = (float*)wsb;                       // 192 KiB
        float*  s2     = (float*)(wsb + 196608);
        float*  t2     = (float*)(wsb + 197632);
        float*  bias2p = (float*)(wsb + 198656);
        ushort* WoH = (ushort*)(wsb + 262144);
        ushort* WoL = (ushort*)(wsb + 524288);
        ushort* W2H = (ushort*)(wsb + 786432);
        ushort* W2L = (ushort*)(wsb + 1048576);
        ushort* W3H = (ushort*)(wsb + 1310720);
        ushort* W3L = (ushort*)(wsb + 1572864);
        float*  yf  = (float*)(wsb + 2 * MB);
        float*  yb  = (float*)(wsb + 66 * MB);
        ushort* s4h = (ushort*)(wsb + 130 * MB);
        ushort* s4l = (ushort*)(wsb + 162 * MB);
        ushort* x1h = (ushort*)(wsb + 2 * MB);    // over yf (dead after combine)
        ushort* x1l = (ushort*)(wsb + 34 * MB);
        ushort* h2h = (ushort*)(wsb + 66 * MB);   // over yb (dead)
        ushort* h2l = (ushort*)(wsb + 130 * MB);  // over s4 planes (dead after G0)

        k_consts<<<dim3(HH * NN2 / 256), dim3(256), 0, stream>>>(log_dt, logA_re, A_im, C_re, C_im, cst);
        k_prep2a<<<dim3(1), dim3(256), 0, stream>>>(g2, b2, m2, v2, s2, t2);
        k_wprep<<<dim3(1536), dim3(256), 0, stream>>>(Wo, W2, W3, s2, WoH, WoL, W2H, W2L, W3H, W3L);
        k_prep2b<<<dim3(2), dim3(256), 0, stream>>>(W2, t2, b2f, bias2p);
        k_scan<<<dim3(BB * HH), dim3(64), 0, stream>>>(x, g1, b1, m1, v1, cst, yf, yb);
        k_combine2<<<dim3(BB * HH * LL / 4 / 256), dim3(256), 0, stream>>>(x, g1, b1, m1, v1, D, yf, yb, s4h, s4l);
        k_mgemm<0><<<dim3(4, 32, 16), dim3(256), 0, stream>>>(WoH, WoL, s4h, s4l, bo, x, out, x1h, x1l);
        k_mgemm<1><<<dim3(4, 32, 16), dim3(256), 0, stream>>>(W2H, W2L, x1h, x1l, bias2p, nullptr, nullptr, h2h, h2l);
        k_mgemm<2><<<dim3(2, 32, 16), dim3(256), 0, stream>>>(W3H, W3L, h2h, h2l, b3, nullptr, out, nullptr, nullptr);
    } else {
        // -------- fallback: validated all-f32 pipeline (round-4) --------
        float* yf  = (float*)wsb;
        float* yb  = (float*)(wsb + 64 * MB);
        float* h2  = (float*)wsb;
        float* cst = (float*)(wsb + 128 * MB);

        k_consts<<<dim3(HH * NN2 / 256), dim3(256), 0, stream>>>(log_dt, logA_re, A_im, C_re, C_im, cst);
        k_scan<<<dim3(BB * HH), dim3(64), 0, stream>>>(x, g1, b1, m1, v1, cst, yf, yb);
        k_combine<<<dim3(BB * HH * LL / 4 / 256), dim3(256), 0, stream>>>(x, g1, b1, m1, v1, D, yb, yf);
        k_gemm<0><<<dim3(4, 64, 16), dim3(256), 0, stream>>>(Wo, yf, bo, x,
                                                             nullptr, nullptr, nullptr, nullptr, out);
        k_gemm<1><<<dim3(4, 64, 16), dim3(256), 0, stream>>>(W2, out, b2f, nullptr,
                                                             g2, b2, m2, v2, h2);
        k_gemm<2><<<dim3(2, 64, 16), dim3(256), 0, stream>>>(W3, h2, b3, out,
                                                             nullptr, nullptr, nullptr, nullptr, out);
    }
}

// Round 9
// 902.705 us; speedup vs baseline: 1.3261x; 1.0880x over previous
//
#include <hip/hip_runtime.h>

#define BB 16
#define HH 256
#define LL 4096
#define NN2 32

using f32x16 = __attribute__((ext_vector_type(16))) float;
using bfx8   = __attribute__((ext_vector_type(8))) short;

static constexpr float BN_EPS = 1e-5f;

__device__ __forceinline__ float gelu_exact(float v) {
    return 0.5f * v * (1.0f + erff(v * 0.70710678118654752f));
}
__device__ __forceinline__ float sigmoidf_(float v) {
    return 1.0f / (1.0f + expf(-v));
}
// f32 -> bf16 (RNE) and back, via bit ops
__device__ __forceinline__ ushort f2bf(float f) {
    uint u = __float_as_uint(f);
    u += 0x7fffu + ((u >> 16) & 1u);
    return (ushort)(u >> 16);
}
__device__ __forceinline__ float bf2f(ushort h) {
    return __uint_as_float(((uint)h) << 16);
}
// LDS B-tile addressing: row l = 12l + 4*((l>>3)&7) + 32*(l>>6)  (validated r7)
__device__ __forceinline__ int rowstart(int l) {
    return l * 12 + ((l >> 3) & 7) * 4 + ((l >> 6) << 5);
}

// ---------------------------------------------------------------------------
// K0: per-(h,n) SSM constants (validated, unchanged).
// ---------------------------------------------------------------------------
__global__ void k_consts(const float* __restrict__ log_dt,
                         const float* __restrict__ logA_re,
                         const float* __restrict__ A_im,
                         const float* __restrict__ C_re,
                         const float* __restrict__ C_im,
                         float* __restrict__ cst) {
    int idx = blockIdx.x * blockDim.x + threadIdx.x;
    if (idx >= HH * NN2) return;
    int h = idx / NN2;
    float dt = expf(log_dt[h]);
    float Ar = -expf(logA_re[idx]);
    float Ai = A_im[idx];
    float er = expf(dt * Ar);
    float wr = er * cosf(dt * Ai);
    float wi = er * sinf(dt * Ai);
    float Er = wr - 1.0f, Ei = wi;
    float inv = 1.0f / (Ar * Ar + Ai * Ai);
    float Fr = (Er * Ar + Ei * Ai) * inv;
    float Fi = (Ei * Ar - Er * Ai) * inv;
    cst[idx] = wr;
    cst[8192 + idx] = wi;
    #pragma unroll
    for (int c = 0; c < 2; ++c) {
        float Cr = C_re[c * HH * NN2 + idx], Ci = C_im[c * HH * NN2 + idx];
        cst[8192 * (2 + 2 * c) + idx] = 2.0f * (Cr * Fr - Ci * Fi);
        cst[8192 * (3 + 2 * c) + idx] = 2.0f * (Cr * Fi + Ci * Fr);
    }
}

// ---------------------------------------------------------------------------
// Preps: BN2 fold + weight hi/lo split (validated, unchanged).
// ---------------------------------------------------------------------------
__global__ void k_prep2a(const float* __restrict__ g2, const float* __restrict__ b2,
                         const float* __restrict__ m2, const float* __restrict__ v2,
                         float* __restrict__ s2, float* __restrict__ t2) {
    int k = threadIdx.x;  // 256
    float s = g2[k] * rsqrtf(v2[k] + BN_EPS);
    s2[k] = s;
    t2[k] = fmaf(-m2[k], s, b2[k]);
}
__global__ void k_prep2b(const float* __restrict__ W2, const float* __restrict__ t2,
                         const float* __restrict__ b2f, float* __restrict__ bias2p) {
    int o = blockIdx.x * 256 + threadIdx.x;  // 512
    float acc = b2f[o];
    for (int k = 0; k < 256; ++k) acc = fmaf(W2[o * 256 + k], t2[k], acc);
    bias2p[o] = acc;
}
__global__ void k_wprep(const float* __restrict__ Wo, const float* __restrict__ W2,
                        const float* __restrict__ W3, const float* __restrict__ s2,
                        ushort* __restrict__ WoH, ushort* __restrict__ WoL,
                        ushort* __restrict__ W2H, ushort* __restrict__ W2L,
                        ushort* __restrict__ W3H, ushort* __restrict__ W3L) {
    int i = blockIdx.x * 256 + threadIdx.x;  // 3 * 131072
    int job = i >> 17, e = i & 131071;
    float w; ushort *H, *L;
    if (job == 0)      { w = Wo[e];                  H = WoH; L = WoL; }
    else if (job == 1) { w = W2[e] * s2[e & 255];    H = W2H; L = W2L; }
    else               { w = W3[e];                  H = W3H; L = W3L; }
    ushort h = f2bf(w);
    H[e] = h;
    L[e] = f2bf(w - bf2f(h));
}

// ---------------------------------------------------------------------------
// K2: bidirectional diagonal-SSM scan, one wave per (b,h) row.
// Round-8 changes vs validated r7 scan:
//  - x comes straight from global as 8 prefetched float4/chunk/lane (L1/L2
//    served; VMEM pipe idle) -> removes the 9 LDS instrs/chunk x round-trip.
//    BN applied inline per element.
//  - outputs stored as bf16 (halves y write+read traffic).
// Transpose via XOR-swizzled [mode][36] tile unchanged (validated).
// LDS: [0..1151] fwd contrib, [1152..2303] bwd contrib (9216 B).
// ---------------------------------------------------------------------------
__global__ __launch_bounds__(64) void k_scan(const float* __restrict__ x,
                                             const float* __restrict__ g1,
                                             const float* __restrict__ b1,
                                             const float* __restrict__ m1,
                                             const float* __restrict__ v1,
                                             const float* __restrict__ cst,
                                             ushort* __restrict__ yf,
                                             ushort* __restrict__ yb) {
    __shared__ float smem[2304];
    int bh = blockIdx.x;
    int h = bh & (HH - 1);
    int lane = threadIdx.x;
    int half = lane >> 5;
    int n = lane & 31;
    int hn = h * NN2 + n;

    float wr = cst[hn];
    float wi = cst[8192 + hn];
    float Cr = cst[8192 * (2 + 2 * half) + hn];
    float Ci = cst[8192 * (3 + 2 * half) + hn];

    float sc = g1[h] * rsqrtf(v1[h] + BN_EPS);
    float sh = fmaf(-m1[h], sc, b1[h]);

    const float* xrow = x + (size_t)bh * LL;
    ushort* yfr = yf + (size_t)bh * LL;
    ushort* ybr = yb + (size_t)bh * LL;

    float sr = 0.0f, si = 0.0f;
    const int hbase = half * 1152;
    const int xsw = (n >> 3) << 2;
    const int lbase = hbase + n * 36;

    // chunk-c, block-t x load: fwd ascending; bwd descending (components
    // arrive reversed: .w = first step of the 4)
    auto ldx = [&](int c, int t) -> float4 {
        return half ? *(const float4*)(xrow + LL - 4 - c * 32 - 4 * t)
                    : *(const float4*)(xrow + c * 32 + 4 * t);
    };

    float4 bufA[8], bufB[8];
    #pragma unroll
    for (int t = 0; t < 8; ++t) bufA[t] = ldx(0, t);

    auto step = [&](float4 (&cur)[8], float4 (&nxt)[8], int c) {
        if (c + 1 < LL / 32) {
            #pragma unroll
            for (int t = 0; t < 8; ++t) nxt[t] = ldx(c + 1, t);
        }
        #pragma unroll
        for (int t = 0; t < 8; ++t) {
            float4 f = cur[t];
            float v0 = half ? f.w : f.x;
            float v1_ = half ? f.z : f.y;
            float v2 = half ? f.y : f.z;
            float v3 = half ? f.x : f.w;
            float4 cb;
            { float xv = fmaf(v0, sc, sh);
              float t0 = fmaf(wr, sr, xv); float ns = fmaf(wi, sr, wr * si);
              sr = fmaf(-wi, si, t0); si = ns; cb.x = fmaf(Cr, sr, -(Ci * si)); }
            { float xv = fmaf(v1_, sc, sh);
              float t0 = fmaf(wr, sr, xv); float ns = fmaf(wi, sr, wr * si);
              sr = fmaf(-wi, si, t0); si = ns; cb.y = fmaf(Cr, sr, -(Ci * si)); }
            { float xv = fmaf(v2, sc, sh);
              float t0 = fmaf(wr, sr, xv); float ns = fmaf(wi, sr, wr * si);
              sr = fmaf(-wi, si, t0); si = ns; cb.z = fmaf(Cr, sr, -(Ci * si)); }
            { float xv = fmaf(v3, sc, sh);
              float t0 = fmaf(wr, sr, xv); float ns = fmaf(wi, sr, wr * si);
              sr = fmaf(-wi, si, t0); si = ns; cb.w = fmaf(Cr, sr, -(Ci * si)); }
            *(float4*)&smem[lbase + ((4 * t) ^ xsw)] = cb;
        }
        __syncthreads();

        float s0 = 0.0f, s1 = 0.0f, s2 = 0.0f, s3 = 0.0f;
        #pragma unroll
        for (int m = 0; m < 32; m += 4) {
            s0 += smem[hbase + (m + 0) * 36 + (n ^ (((m + 0) >> 3) << 2))];
            s1 += smem[hbase + (m + 1) * 36 + (n ^ (((m + 1) >> 3) << 2))];
            s2 += smem[hbase + (m + 2) * 36 + (n ^ (((m + 2) >> 3) << 2))];
            s3 += smem[hbase + (m + 3) * 36 + (n ^ (((m + 3) >> 3) << 2))];
        }
        float sum = (s0 + s1) + (s2 + s3);
        int gl = c * 32 + n;
        if (half) {
            int oidx = LL - 2 - gl;
            if (oidx >= 0) ybr[oidx] = f2bf(sum);
        } else {
            yfr[gl] = f2bf(sum);
        }
        __syncthreads();
    };

    for (int c = 0; c < LL / 32; c += 2) {
        step(bufA, bufB, c);
        step(bufB, bufA, c + 1);
    }
}

// ---------------------------------------------------------------------------
// K2b: combine -> single bf16 plane s4h. yb[row][L-1] unwritten -> masked.
// ---------------------------------------------------------------------------
__global__ void k_combine2(const float* __restrict__ x,
                           const float* __restrict__ g1, const float* __restrict__ b1,
                           const float* __restrict__ m1, const float* __restrict__ v1,
                           const float* __restrict__ D,
                           const ushort* __restrict__ yf, const ushort* __restrict__ yb,
                           ushort* __restrict__ s4h) {
    int i4 = blockIdx.x * blockDim.x + threadIdx.x;
    if (i4 >= BB * HH * LL / 4) return;
    int row = i4 >> 10;
    int h = row & (HH - 1);
    float sc = g1[h] * rsqrtf(v1[h] + BN_EPS);
    float sh = fmaf(-m1[h], sc, b1[h]);
    float d = D[h];
    float4 xv = ((const float4*)x)[i4];
    ushort4 fu = ((const ushort4*)yf)[i4];
    ushort4 bu = ((const ushort4*)yb)[i4];
    if ((i4 & 1023) == 1023) bu.w = 0;   // yb[L-1] unwritten
    float v0 = gelu_exact(fmaf(d, fmaf(xv.x, sc, sh), bf2f(fu.x) + bf2f(bu.x)));
    float v1_ = gelu_exact(fmaf(d, fmaf(xv.y, sc, sh), bf2f(fu.y) + bf2f(bu.y)));
    float v2 = gelu_exact(fmaf(d, fmaf(xv.z, sc, sh), bf2f(fu.z) + bf2f(bu.z)));
    float v3 = gelu_exact(fmaf(d, fmaf(xv.w, sc, sh), bf2f(fu.w) + bf2f(bu.w)));
    ushort4 hh;
    hh.x = f2bf(v0); hh.y = f2bf(v1_); hh.z = f2bf(v2); hh.w = f2bf(v3);
    ((ushort4*)s4h)[i4] = hh;
}

// ---------------------------------------------------------------------------
// Split-weight MFMA GEMM (act hi-plane only). Block = 4 waves, 128o x 128l,
// K-chunk 16. z = (Wh+Wl)@bf16(act): 2 MFMAs per frag (exact in W, act
// rounded to bf16 — error ~0.002 abs, see r8 analysis).
// B staged to LDS with k-pair transpose (validated r7 addressing), single
// plane, all 256 threads staging (each 2x uint2 load + 4 b32 writes).
// MODE 0: z = Wo@s4 + bo; GLU via LDS gate exchange; x1 = x + glu ->
//         d_out (f32) + x1h (bf16).
// MODE 1: h2 = gelu(W2s@x1 + bias2p) -> h2h (bf16).
// MODE 2: d_out += W3@h2 + b3 (in-place, K=512).
// ---------------------------------------------------------------------------
template <int MODE>
__global__ __launch_bounds__(256) void k_mgemm(
    const ushort* __restrict__ Ah, const ushort* __restrict__ Al,
    const ushort* __restrict__ Bh,
    const float* __restrict__ bias,
    const float* __restrict__ X,
    float* __restrict__ Outf,
    ushort* __restrict__ Oh) {

    constexpr int K  = (MODE == 2) ? 512 : 256;
    constexpr int NK = K / 16;

    __shared__ uint bt[1600];
    __shared__ float gatebuf[(MODE == 0) ? 8192 : 4];

    const int tid  = threadIdx.x;
    const int lane = tid & 63;
    const int w    = tid >> 6;
    const int c31  = lane & 31;
    const int g    = lane >> 5;
    const int gm   = blockIdx.x;
    const int l0   = blockIdx.y * 128;
    const int b    = blockIdx.z;

    int r = w * 32 + c31;
    int arow;
    if (MODE == 0) arow = (r < 64) ? (gm * 64 + r) : (256 + gm * 64 + (r - 64));
    else           arow = gm * 128 + r;
    const ushort* apH = Ah + (size_t)arow * K;
    const ushort* apL = Al + (size_t)arow * K;

    // B staging: 256 threads, 1 plane; thread = (kp, lg, hi-half of 8 l's)
    const int tt = tid & 127;
    const int hi = tid >> 7;
    const int kp = tt & 7;
    const int lg = tt >> 3;
    const int j0 = hi * 4;
    const ushort* bbase = Bh + ((size_t)b * K + 2 * kp) * LL + l0 + lg * 8 + hi * 4;
    const int wb = 96 * lg + 4 * (lg & 7) + 32 * (lg >> 3);   // rowstart(lg*8)
    const int sl0 = (kp & 3) + 4 * (kp >> 2);
    const int sl1 = (kp & 3) + 4 * ((kp >> 2) ^ 1);

    f32x16 acc[4];
    #pragma unroll
    for (int f = 0; f < 4; ++f)
        #pragma unroll
        for (int e = 0; e < 16; ++e) acc[f][e] = 0.0f;

    uint2 r0 = *(const uint2*)(bbase);
    uint2 r1 = *(const uint2*)(bbase + LL);

    for (int kc = 0; kc < NK; ++kc) {
        __syncthreads();   // WAR: previous chunk's readers done
        {
            uint p0 = (r0.x & 0xffffu) | (r1.x << 16);
            uint p1 = (r0.x >> 16)     | (r1.x & 0xffff0000u);
            uint p2 = (r0.y & 0xffffu) | (r1.y << 16);
            uint p3 = (r0.y >> 16)     | (r1.y & 0xffff0000u);
            bt[wb + 12 * (j0 + 0) + sl0] = p0;
            bt[wb + 12 * (j0 + 1) + sl1] = p1;
            bt[wb + 12 * (j0 + 2) + sl0] = p2;
            bt[wb + 12 * (j0 + 3) + sl1] = p3;
        }
        __syncthreads();
        if (kc + 1 < NK) {
            const ushort* nb = bbase + (size_t)((kc + 1) * 16) * LL;
            r0 = *(const uint2*)(nb);
            r1 = *(const uint2*)(nb + LL);
        }
        bfx8 ah = *(const bfx8*)(apH + kc * 16 + 8 * g);
        bfx8 al = *(const bfx8*)(apL + kc * 16 + 8 * g);
        #pragma unroll
        for (int f = 0; f < 4; ++f) {
            int l = f * 32 + c31;
            int ra = rowstart(l) + ((g ^ (l & 1)) << 2);
            bfx8 bhf = *(const bfx8*)(bt + ra);
            acc[f] = __builtin_amdgcn_mfma_f32_32x32x16_bf16(ah, bhf, acc[f], 0, 0, 0);
            acc[f] = __builtin_amdgcn_mfma_f32_32x32x16_bf16(al, bhf, acc[f], 0, 0, 0);
        }
    }

    // ------------------------------ epilogue ------------------------------
    if (MODE == 0) {
        if (w >= 2) {   // gate waves: sigmoid -> LDS
            int grow_base = (w - 2) * 32;
            int og_base = 256 + gm * 64 + grow_base;
            #pragma unroll
            for (int f = 0; f < 4; ++f)
                #pragma unroll
                for (int reg = 0; reg < 16; ++reg) {
                    int rr = (reg & 3) + 8 * (reg >> 2) + 4 * g;
                    float zg = acc[f][reg] + bias[og_base + rr];
                    gatebuf[(grow_base + rr) * 128 + f * 32 + c31] = sigmoidf_(zg);
                }
        }
        __syncthreads();
        if (w < 2) {    // value waves: GLU + residual + stores
            int vr_base = w * 32;
            #pragma unroll
            for (int f = 0; f < 4; ++f)
                #pragma unroll
                for (int reg = 0; reg < 16; ++reg) {
                    int rr = (reg & 3) + 8 * (reg >> 2) + 4 * g;
                    int vr = vr_base + rr;
                    int ov = gm * 64 + vr;
                    size_t oi = ((size_t)b * HH + ov) * LL + l0 + f * 32 + c31;
                    float zv = acc[f][reg] + bias[ov];
                    float res = X[oi] + zv * gatebuf[vr * 128 + f * 32 + c31];
                    Outf[oi] = res;
                    Oh[oi] = f2bf(res);
                }
        }
    } else if (MODE == 1) {
        #pragma unroll
        for (int f = 0; f < 4; ++f)
            #pragma unroll
            for (int reg = 0; reg < 16; ++reg) {
                int rr = (reg & 3) + 8 * (reg >> 2) + 4 * g;
                int o = gm * 128 + w * 32 + rr;
                size_t oi = ((size_t)b * 512 + o) * LL + l0 + f * 32 + c31;
                float v = gelu_exact(acc[f][reg] + bias[o]);
                Oh[oi] = f2bf(v);
            }
    } else {
        #pragma unroll
        for (int f = 0; f < 4; ++f)
            #pragma unroll
            for (int reg = 0; reg < 16; ++reg) {
                int rr = (reg & 3) + 8 * (reg >> 2) + 4 * g;
                int o = gm * 128 + w * 32 + rr;
                size_t oi = ((size_t)b * HH + o) * LL + l0 + f * 32 + c31;
                Outf[oi] = Outf[oi] + acc[f][reg] + bias[o];
            }
    }
}

// ---------------------------------------------------------------------------
extern "C" void kernel_launch(void* const* d_in, const int* in_sizes, int n_in,
                              void* d_out, int out_size, void* d_ws, size_t ws_size,
                              hipStream_t stream) {
    const float* x       = (const float*)d_in[0];
    const float* g1      = (const float*)d_in[1];
    const float* b1      = (const float*)d_in[2];
    const float* m1      = (const float*)d_in[3];
    const float* v1      = (const float*)d_in[4];
    const float* log_dt  = (const float*)d_in[5];
    const float* logA_re = (const float*)d_in[6];
    const float* A_im    = (const float*)d_in[7];
    const float* C_re    = (const float*)d_in[8];
    const float* C_im    = (const float*)d_in[9];
    const float* D       = (const float*)d_in[10];
    const float* Wo      = (const float*)d_in[11];
    const float* bo      = (const float*)d_in[12];
    const float* g2      = (const float*)d_in[13];
    const float* b2      = (const float*)d_in[14];
    const float* m2      = (const float*)d_in[15];
    const float* v2      = (const float*)d_in[16];
    const float* W2      = (const float*)d_in[17];
    const float* b2f     = (const float*)d_in[18];
    const float* W3      = (const float*)d_in[19];
    const float* b3      = (const float*)d_in[20];
    float* out = (float*)d_out;
    char* wsb = (char*)d_ws;

    const size_t MB = 1024 * 1024;

    // flat ws layout (194 MB, proven available r5/r7):
    float*  cst    = (float*)wsb;                       // 192 KiB
    float*  s2     = (float*)(wsb + 196608);
    float*  t2     = (float*)(wsb + 197632);
    float*  bias2p = (float*)(wsb + 198656);
    ushort* WoH = (ushort*)(wsb + 262144);
    ushort* WoL = (ushort*)(wsb + 524288);
    ushort* W2H = (ushort*)(wsb + 786432);
    ushort* W2L = (ushort*)(wsb + 1048576);
    ushort* W3H = (ushort*)(wsb + 1310720);
    ushort* W3L = (ushort*)(wsb + 1572864);
    ushort* yf  = (ushort*)(wsb + 2 * MB);     //  2.. 34 MB (bf16)
    ushort* yb  = (ushort*)(wsb + 34 * MB);    // 34.. 66 MB (bf16)
    ushort* s4h = (ushort*)(wsb + 66 * MB);    // 66.. 98 MB
    ushort* x1h = (ushort*)(wsb + 98 * MB);    // 98..130 MB
    ushort* h2h = (ushort*)(wsb + 130 * MB);   // 130..194 MB (512ch)

    k_consts<<<dim3(HH * NN2 / 256), dim3(256), 0, stream>>>(log_dt, logA_re, A_im, C_re, C_im, cst);
    k_prep2a<<<dim3(1), dim3(256), 0, stream>>>(g2, b2, m2, v2, s2, t2);
    k_wprep<<<dim3(1536), dim3(256), 0, stream>>>(Wo, W2, W3, s2, WoH, WoL, W2H, W2L, W3H, W3L);
    k_prep2b<<<dim3(2), dim3(256), 0, stream>>>(W2, t2, b2f, bias2p);
    k_scan<<<dim3(BB * HH), dim3(64), 0, stream>>>(x, g1, b1, m1, v1, cst, yf, yb);
    k_combine2<<<dim3(BB * HH * LL / 4 / 256), dim3(256), 0, stream>>>(x, g1, b1, m1, v1, D, yf, yb, s4h);
    // residual 1: x1 = x + glu(Wo @ s4 + bo) -> d_out (f32) + x1h (bf16)
    k_mgemm<0><<<dim3(4, 32, 16), dim3(256), 0, stream>>>(WoH, WoL, s4h, bo, x, out, x1h);
    // FFN hidden: h2 = gelu(W2s @ x1 + bias2p) -> h2h (bf16)
    k_mgemm<1><<<dim3(4, 32, 16), dim3(256), 0, stream>>>(W2H, W2L, x1h, bias2p, nullptr, nullptr, h2h);
    // final: out += W3 @ h2 + b3 (in-place f32)
    k_mgemm<2><<<dim3(2, 32, 16), dim3(256), 0, stream>>>(W3H, W3L, h2h, b3, nullptr, out, nullptr);
}